// Round 1
// baseline (44.967 us; speedup 1.0000x reference)
//
#include <hip/hip_runtime.h>

// Matvec: out[s] = dot(encoder_out[s, :], decoder_hidden[L-1, :])
// S=16384, H=4096, fp32. Memory-bound: 256 MiB encoder read dominates.

constexpr int H = 4096;

__global__ __launch_bounds__(256) void matvec_dot_kernel(
    const float* __restrict__ enc,    // [S, H]
    const float* __restrict__ target, // [H] (already offset to last layer)
    float* __restrict__ out,          // [S]
    int S)
{
    __shared__ float tgt[H];

    // Stage target vector into LDS once per block (float4 = 16B/lane).
    {
        const float4* tsrc = reinterpret_cast<const float4*>(target);
        float4* tdst = reinterpret_cast<float4*>(tgt);
        for (int i = threadIdx.x; i < H / 4; i += blockDim.x)
            tdst[i] = tsrc[i];
    }
    __syncthreads();

    const int lane = threadIdx.x & 63;
    const int waveInBlock = threadIdx.x >> 6;
    const int wavesPerBlock = blockDim.x >> 6;
    const int globalWave = blockIdx.x * wavesPerBlock + waveInBlock;
    const int numWaves = gridDim.x * wavesPerBlock;

    const float4* tlds = reinterpret_cast<const float4*>(tgt);

    for (int row = globalWave; row < S; row += numWaves) {
        const float4* rowp =
            reinterpret_cast<const float4*>(enc + (size_t)row * H);
        float acc = 0.0f;
        // H/4 float4 elements, 64 lanes -> 16 iterations, fully coalesced.
        #pragma unroll
        for (int it = 0; it < (H / 4) / 64; ++it) {
            float4 a = rowp[it * 64 + lane];
            float4 b = tlds[it * 64 + lane];
            acc += a.x * b.x + a.y * b.y + a.z * b.z + a.w * b.w;
        }
        // 64-lane butterfly reduction.
        #pragma unroll
        for (int off = 32; off > 0; off >>= 1)
            acc += __shfl_xor(acc, off, 64);
        if (lane == 0) out[row] = acc;
    }
}

extern "C" void kernel_launch(void* const* d_in, const int* in_sizes, int n_in,
                              void* d_out, int out_size, void* d_ws, size_t ws_size,
                              hipStream_t stream) {
    const float* enc = (const float*)d_in[0];           // [S, H] fp32
    const float* dec = (const float*)d_in[1];           // [L, H] fp32
    float* out = (float*)d_out;                          // [S] fp32

    const int S = out_size;                              // 16384
    const int target_off = in_sizes[1] - H;              // last layer row
    const float* target = dec + target_off;

    const int block = 256;
    const int grid = 1024;  // 4 blocks/CU, grid-stride over rows
    matvec_dot_kernel<<<grid, block, 0, stream>>>(enc, target, out, S);
}